// Round 1
// baseline (492.075 us; speedup 1.0000x reference)
//
#include <hip/hip_runtime.h>
#include <math.h>

constexpr float EPS = 1e-5f;
constexpr float SCALE = 0.08838834764831845f; // 1/sqrt(128)

using f32x4  = __attribute__((ext_vector_type(4))) float;
using bf16x8 = __attribute__((ext_vector_type(8))) short;
using us8    = __attribute__((ext_vector_type(8))) unsigned short;

__device__ __forceinline__ unsigned short f2b_rne(float f) {
    unsigned int x = __float_as_uint(f);
    return (unsigned short)((x + 0x7fffu + ((x >> 16) & 1u)) >> 16);
}
__device__ __forceinline__ float b2f(unsigned short u) {
    return __uint_as_float(((unsigned int)u) << 16);
}

// ================= one-time weight split: fp32 -> (hi, lo) bf16 planes =======
// Wp (24576) | Wk (16384) | Wv (16384) packed contiguously.
__global__ __launch_bounds__(256) void split_weights_kernel(
    const float* __restrict__ Wp, const float* __restrict__ Wk,
    const float* __restrict__ Wv, unsigned short* __restrict__ hi,
    unsigned short* __restrict__ lo)
{
    int idx = blockIdx.x * 256 + threadIdx.x; // 57344 total
    float v;
    if (idx < 24576)      v = Wp[idx];
    else if (idx < 40960) v = Wk[idx - 24576];
    else                  v = Wv[idx - 40960];
    unsigned int bits = __float_as_uint(v);
    hi[idx] = (unsigned short)(bits >> 16);
    lo[idx] = f2b_rne(v - __uint_as_float(bits & 0xffff0000u));
}

// ============== split-precision bf16 MFMA GEMM: out = A @ W^T + bias =========
// Each fp32 operand = hi + lo (bf16); product via 3 MFMAs (hh + hl + lh) ->
// ~2^-17 relative error, effectively fp32. Tile 128x128, BK=32, 4 waves.
// Used for GEMM1 only (patch -> LN'd inputs, hi/lo planes out).
template<int KDIM, bool A_PRESPLIT, bool DO_LN, bool OUT_SPLIT>
__global__ __launch_bounds__(256, 2) void gemm_split_kernel(
    const void* __restrict__ Av, const unsigned short* __restrict__ Alo,
    const unsigned short* __restrict__ Bhi, const unsigned short* __restrict__ Blo,
    const float* __restrict__ bias, const float* __restrict__ gamma,
    const float* __restrict__ beta, float* __restrict__ outf,
    unsigned short* __restrict__ out_hi, unsigned short* __restrict__ out_lo)
{
    __shared__ __align__(16) unsigned short Ah[128 * 32], Al[128 * 32];
    __shared__ __align__(16) unsigned short Bh[128 * 32], Bl[128 * 32];

    const int tid  = threadIdx.x;
    const int lane = tid & 63, wave = tid >> 6;
    const int ln15 = lane & 15, quad = lane >> 4;
    const int m0   = blockIdx.x * 128;
    const int wrow = wave * 32;

    f32x4 acc[2][8];
#pragma unroll
    for (int mt = 0; mt < 2; mt++)
#pragma unroll
        for (int nt = 0; nt < 8; nt++)
#pragma unroll
            for (int r = 0; r < 4; r++) acc[mt][nt][r] = 0.f;

    for (int kk = 0; kk < KDIM; kk += 32) {
        // ---- stage A tile (128 x 32) hi/lo ----
#pragma unroll
        for (int c = tid; c < 512; c += 256) {
            int m = c >> 2, ko = (c & 3) * 8;
            if (A_PRESPLIT) {
                size_t off = (size_t)(m0 + m) * KDIM + kk + ko;
                *(us8*)&Ah[c * 8] = *(const us8*)((const unsigned short*)Av + off);
                *(us8*)&Al[c * 8] = *(const us8*)(Alo + off);
            } else {
                const float* src = (const float*)Av + (size_t)(m0 + m) * KDIM + kk + ko;
                float4 x = *(const float4*)src;
                float4 y = *(const float4*)(src + 4);
                float vv[8] = {x.x, x.y, x.z, x.w, y.x, y.y, y.z, y.w};
                us8 h, l;
#pragma unroll
                for (int j = 0; j < 8; j++) {
                    unsigned int bits = __float_as_uint(vv[j]);
                    h[j] = (unsigned short)(bits >> 16);
                    l[j] = f2b_rne(vv[j] - __uint_as_float(bits & 0xffff0000u));
                }
                *(us8*)&Ah[c * 8] = h;
                *(us8*)&Al[c * 8] = l;
            }
        }
        // ---- stage B tile = W rows (128 x 32), pre-split ----
#pragma unroll
        for (int c = tid; c < 512; c += 256) {
            int n = c >> 2, ko = (c & 3) * 8;
            size_t off = (size_t)n * KDIM + kk + ko;
            *(us8*)&Bh[c * 8] = *(const us8*)(Bhi + off);
            *(us8*)&Bl[c * 8] = *(const us8*)(Blo + off);
        }
        __syncthreads();

        bf16x8 ah[2], al[2];
#pragma unroll
        for (int mt = 0; mt < 2; mt++) {
            int o = (wrow + mt * 16 + ln15) * 32 + quad * 8;
            ah[mt] = *(const bf16x8*)&Ah[o];
            al[mt] = *(const bf16x8*)&Al[o];
        }
#pragma unroll
        for (int nt = 0; nt < 8; nt++) {
            int o = (nt * 16 + ln15) * 32 + quad * 8;
            bf16x8 bh = *(const bf16x8*)&Bh[o];
            bf16x8 bl = *(const bf16x8*)&Bl[o];
#pragma unroll
            for (int mt = 0; mt < 2; mt++) {
                acc[mt][nt] = __builtin_amdgcn_mfma_f32_16x16x32_bf16(ah[mt], bh, acc[mt][nt], 0, 0, 0);
                acc[mt][nt] = __builtin_amdgcn_mfma_f32_16x16x32_bf16(ah[mt], bl, acc[mt][nt], 0, 0, 0);
                acc[mt][nt] = __builtin_amdgcn_mfma_f32_16x16x32_bf16(al[mt], bh, acc[mt][nt], 0, 0, 0);
            }
        }
        __syncthreads();
    }

    // ---- epilogue: bias (+ LN) -> store ----
    float bb[8], gg[8], be[8];
#pragma unroll
    for (int nt = 0; nt < 8; nt++) {
        int col = nt * 16 + ln15;
        bb[nt] = bias[col];
        if (DO_LN) { gg[nt] = gamma[col]; be[nt] = beta[col]; }
    }
#pragma unroll
    for (int mt = 0; mt < 2; mt++)
#pragma unroll
        for (int nt = 0; nt < 8; nt++)
#pragma unroll
            for (int r = 0; r < 4; r++) acc[mt][nt][r] += bb[nt];

    float mu[2][4], rs[2][4];
    if (DO_LN) {
        // C/D layout: row = quad*4 + r, col = nt*16 + ln15. A row's 128 cols
        // live in the 16 lanes of one quad across the 8 nt tiles.
#pragma unroll
        for (int mt = 0; mt < 2; mt++)
#pragma unroll
            for (int r = 0; r < 4; r++) {
                float s = 0.f, s2 = 0.f;
#pragma unroll
                for (int nt = 0; nt < 8; nt++) {
                    float v = acc[mt][nt][r];
                    s += v; s2 += v * v;
                }
#pragma unroll
                for (int off = 1; off < 16; off <<= 1) {
                    s  += __shfl_xor(s,  off, 64);
                    s2 += __shfl_xor(s2, off, 64);
                }
                float m = s * (1.f / 128.f);
                mu[mt][r] = m;
                rs[mt][r] = rsqrtf(s2 * (1.f / 128.f) - m * m + EPS);
            }
    }

#pragma unroll
    for (int mt = 0; mt < 2; mt++)
#pragma unroll
        for (int nt = 0; nt < 8; nt++)
#pragma unroll
            for (int r = 0; r < 4; r++) {
                float v = acc[mt][nt][r];
                if (DO_LN) v = (v - mu[mt][r]) * rs[mt][r] * gg[nt] + be[nt];
                size_t o = (size_t)(m0 + wrow + mt * 16 + quad * 4 + r) * 128 + nt * 16 + ln15;
                if (OUT_SPLIT) {
                    unsigned int bits = __float_as_uint(v);
                    out_hi[o] = (unsigned short)(bits >> 16);
                    out_lo[o] = f2b_rne(v - __uint_as_float(bits & 0xffff0000u));
                } else {
                    outf[o] = v;
                }
            }
}

// ======= fused dual GEMM: k = A@Wk^T + bk, v = A@Wv^T + bv (A staged once) ===
// A = LN'd inputs as pre-split hi/lo bf16 planes, KDIM = 128. Bit-identical
// math to running the two GEMMs separately (same 3-MFMA split, same order).
// LDS 48 KB -> 2 blocks/CU; acc 2x64 VGPRs fits the 256-VGPR cap.
__global__ __launch_bounds__(256, 2) void gemm_kv_kernel(
    const unsigned short* __restrict__ Ahi, const unsigned short* __restrict__ Alo,
    const unsigned short* __restrict__ Bkhi, const unsigned short* __restrict__ Bklo,
    const unsigned short* __restrict__ Bvhi, const unsigned short* __restrict__ Bvlo,
    const float* __restrict__ bk, const float* __restrict__ bv,
    float* __restrict__ kout, float* __restrict__ vout)
{
    __shared__ __align__(16) unsigned short Ah[128 * 32], Al[128 * 32];
    __shared__ __align__(16) unsigned short Bh[2][128 * 32], Bl[2][128 * 32];

    const int tid  = threadIdx.x;
    const int lane = tid & 63, wave = tid >> 6;
    const int ln15 = lane & 15, quad = lane >> 4;
    const int m0   = blockIdx.x * 128;
    const int wrow = wave * 32;

    f32x4 acc[2][2][8]; // [kv][mt][nt]
#pragma unroll
    for (int s = 0; s < 2; s++)
#pragma unroll
        for (int mt = 0; mt < 2; mt++)
#pragma unroll
            for (int nt = 0; nt < 8; nt++)
#pragma unroll
                for (int r = 0; r < 4; r++) acc[s][mt][nt][r] = 0.f;

    for (int kk = 0; kk < 128; kk += 32) {
        // ---- stage A tile (128 x 32) hi/lo, read ONCE for both outputs ----
#pragma unroll
        for (int c = tid; c < 512; c += 256) {
            int m = c >> 2, ko = (c & 3) * 8;
            size_t off = (size_t)(m0 + m) * 128 + kk + ko;
            *(us8*)&Ah[c * 8] = *(const us8*)(Ahi + off);
            *(us8*)&Al[c * 8] = *(const us8*)(Alo + off);
        }
        // ---- stage Wk and Wv tiles (128 x 32 each), pre-split ----
#pragma unroll
        for (int c = tid; c < 512; c += 256) {
            int n = c >> 2, ko = (c & 3) * 8;
            size_t off = (size_t)n * 128 + kk + ko;
            *(us8*)&Bh[0][c * 8] = *(const us8*)(Bkhi + off);
            *(us8*)&Bl[0][c * 8] = *(const us8*)(Bklo + off);
            *(us8*)&Bh[1][c * 8] = *(const us8*)(Bvhi + off);
            *(us8*)&Bl[1][c * 8] = *(const us8*)(Bvlo + off);
        }
        __syncthreads();

        bf16x8 ah[2], al[2];
#pragma unroll
        for (int mt = 0; mt < 2; mt++) {
            int o = (wrow + mt * 16 + ln15) * 32 + quad * 8;
            ah[mt] = *(const bf16x8*)&Ah[o];
            al[mt] = *(const bf16x8*)&Al[o];
        }
#pragma unroll
        for (int nt = 0; nt < 8; nt++) {
            int o = (nt * 16 + ln15) * 32 + quad * 8;
            bf16x8 bkh = *(const bf16x8*)&Bh[0][o];
            bf16x8 bkl = *(const bf16x8*)&Bl[0][o];
            bf16x8 bvh = *(const bf16x8*)&Bh[1][o];
            bf16x8 bvl = *(const bf16x8*)&Bl[1][o];
#pragma unroll
            for (int mt = 0; mt < 2; mt++) {
                acc[0][mt][nt] = __builtin_amdgcn_mfma_f32_16x16x32_bf16(ah[mt], bkh, acc[0][mt][nt], 0, 0, 0);
                acc[0][mt][nt] = __builtin_amdgcn_mfma_f32_16x16x32_bf16(ah[mt], bkl, acc[0][mt][nt], 0, 0, 0);
                acc[0][mt][nt] = __builtin_amdgcn_mfma_f32_16x16x32_bf16(al[mt], bkh, acc[0][mt][nt], 0, 0, 0);
                acc[1][mt][nt] = __builtin_amdgcn_mfma_f32_16x16x32_bf16(ah[mt], bvh, acc[1][mt][nt], 0, 0, 0);
                acc[1][mt][nt] = __builtin_amdgcn_mfma_f32_16x16x32_bf16(ah[mt], bvl, acc[1][mt][nt], 0, 0, 0);
                acc[1][mt][nt] = __builtin_amdgcn_mfma_f32_16x16x32_bf16(al[mt], bvh, acc[1][mt][nt], 0, 0, 0);
            }
        }
        __syncthreads();
    }

    // ---- epilogue: bias -> store both outputs fp32 ----
    float bbk[8], bbv[8];
#pragma unroll
    for (int nt = 0; nt < 8; nt++) {
        int col = nt * 16 + ln15;
        bbk[nt] = bk[col];
        bbv[nt] = bv[col];
    }
#pragma unroll
    for (int mt = 0; mt < 2; mt++)
#pragma unroll
        for (int nt = 0; nt < 8; nt++)
#pragma unroll
            for (int r = 0; r < 4; r++) {
                size_t o = (size_t)(m0 + wrow + mt * 16 + quad * 4 + r) * 128 + nt * 16 + ln15;
                kout[o] = acc[0][mt][nt][r] + bbk[nt];
                vout[o] = acc[1][mt][nt][r] + bbv[nt];
            }
}

// =================== init slots + LN + q (one block per slot row) ============
__global__ __launch_bounds__(128) void init_lnq_kernel(
    const float* __restrict__ noise, const float* __restrict__ smu,
    const float* __restrict__ sls, const float* __restrict__ g_s,
    const float* __restrict__ b_s, const float* __restrict__ Wq,
    const float* __restrict__ bq, float* __restrict__ slots,
    float* __restrict__ q)
{
    __shared__ float s_l[128];
    __shared__ float red[4];
    const int row = blockIdx.x, tid = threadIdx.x;
    const int k = row % 3;
    float x = smu[k * 128 + tid] + expf(sls[k * 128 + tid]) * noise[row * 128 + tid];
    slots[row * 128 + tid] = x;

    float s = x, s2 = x * x;
#pragma unroll
    for (int off = 32; off >= 1; off >>= 1) {
        s += __shfl_down(s, off, 64); s2 += __shfl_down(s2, off, 64);
    }
    if ((tid & 63) == 0) { red[tid >> 6] = s; red[2 + (tid >> 6)] = s2; }
    __syncthreads();
    float S = red[0] + red[1], S2 = red[2] + red[3];
    float m = S * (1.f / 128.f);
    float r = rsqrtf(S2 * (1.f / 128.f) - m * m + EPS);
    s_l[tid] = (x - m) * r * g_s[tid] + b_s[tid];
    __syncthreads();

    const float4* wr = (const float4*)&Wq[(size_t)tid * 128];
    float a = bq[tid];
#pragma unroll 8
    for (int d4 = 0; d4 < 32; d4++) {
        float4 w = wr[d4];
        a += s_l[4 * d4] * w.x + s_l[4 * d4 + 1] * w.y
           + s_l[4 * d4 + 2] * w.z + s_l[4 * d4 + 3] * w.w;
    }
    q[row * 128 + tid] = a;
}

// ============ fused attention: logits -> softmax(K=3) -> partial updates =====
// fp32 k/v; per-chunk partial outputs (no atomics/memset).
__global__ __launch_bounds__(256) void attn_kernel(
    const float* __restrict__ q, const float* __restrict__ kbuf,
    const float* __restrict__ vbuf, float* __restrict__ upd_part,
    float* __restrict__ attn_out, int write_attn)
{
    __shared__ float q_l[3][128];
    __shared__ __align__(16) float kv[64][132];
    __shared__ float lg[3][64];
    __shared__ float w_l[3][64];
    const int b = blockIdx.y, chunk = blockIdx.x, n0 = chunk * 64, tid = threadIdx.x;

    for (int idx = tid; idx < 384; idx += 256)
        q_l[idx >> 7][idx & 127] = q[b * 384 + idx];

    const float4* kg = (const float4*)(kbuf + ((size_t)b * 1024 + n0) * 128);
    for (int idx = tid; idx < 2048; idx += 256) {
        int n = idx >> 5, c = (idx & 31) * 4;
        *(float4*)&kv[n][c] = kg[idx];
    }
    __syncthreads();

    { // logits: thread = (token n, quarter q4); all 256 threads active
        int n = tid >> 2, q4 = tid & 3;
        const float* kr = &kv[n][q4 * 32];
        const float* q0 = &q_l[0][q4 * 32];
        const float* q1 = &q_l[1][q4 * 32];
        const float* q2 = &q_l[2][q4 * 32];
        float p0 = 0.f, p1 = 0.f, p2 = 0.f;
#pragma unroll 8
        for (int i = 0; i < 32; i++) {
            float vv = kr[i];
            p0 += q0[i] * vv; p1 += q1[i] * vv; p2 += q2[i] * vv;
        }
        p0 += __shfl_xor(p0, 1, 64); p0 += __shfl_xor(p0, 2, 64);
        p1 += __shfl_xor(p1, 1, 64); p1 += __shfl_xor(p1, 2, 64);
        p2 += __shfl_xor(p2, 1, 64); p2 += __shfl_xor(p2, 2, 64);
        if (q4 == 0) {
            lg[0][n] = p0 * SCALE; lg[1][n] = p1 * SCALE; lg[2][n] = p2 * SCALE;
        }
    }
    __syncthreads();

    if (tid < 64) { // softmax over the 3 slots for token n=tid
        float l0 = lg[0][tid], l1 = lg[1][tid], l2 = lg[2][tid];
        float m = fmaxf(l0, fmaxf(l1, l2));
        float e0 = expf(l0 - m), e1 = expf(l1 - m), e2 = expf(l2 - m);
        float inv = 1.f / (e0 + e1 + e2);
        w_l[0][tid] = e0 * inv; w_l[1][tid] = e1 * inv; w_l[2][tid] = e2 * inv;
        if (write_attn) {
            attn_out[b * 3072 + n0 + tid]        = e0 * inv;
            attn_out[b * 3072 + 1024 + n0 + tid] = e1 * inv;
            attn_out[b * 3072 + 2048 + n0 + tid] = e2 * inv;
        }
    }
    const float4* vg = (const float4*)(vbuf + ((size_t)b * 1024 + n0) * 128);
    for (int idx = tid; idx < 2048; idx += 256) {
        int n = idx >> 5, c = (idx & 31) * 4;
        *(float4*)&kv[n][c] = vg[idx];
    }
    __syncthreads();

    if (tid < 128) {
        float p0 = 0.f, p1 = 0.f, p2 = 0.f;
#pragma unroll 8
        for (int n = 0; n < 64; n++) {
            float vv = kv[n][tid];
            p0 += w_l[0][n] * vv; p1 += w_l[1][n] * vv; p2 += w_l[2][n] * vv;
        }
        size_t base = (((size_t)b * 16 + chunk) * 3) * 128 + tid;
        upd_part[base]       = p0;
        upd_part[base + 128] = p1;
        upd_part[base + 256] = p2;
    }
}

// ====== fused GRU cell + LN + MLP residual + (LN_s + q for next iter) ========
__global__ __launch_bounds__(128) void gru_mlp_kernel(
    const float* __restrict__ slots_in, const float* __restrict__ upd_part,
    const float* __restrict__ Wih, const float* __restrict__ bih,
    const float* __restrict__ Whh, const float* __restrict__ bhh,
    const float* __restrict__ g_m, const float* __restrict__ b_m,
    const float* __restrict__ W1, const float* __restrict__ b1,
    const float* __restrict__ W2, const float* __restrict__ b2,
    const float* __restrict__ g_s, const float* __restrict__ b_s,
    const float* __restrict__ Wq, const float* __restrict__ bq,
    float* __restrict__ slots_out, float* __restrict__ q_out, int write_q)
{
    __shared__ float u_l[128], h_l[128], n_l[128], hid_l[256];
    __shared__ float red[4];
    const int row = blockIdx.x, tid = threadIdx.x;
    const int bb_ = row / 3, ss = row - bb_ * 3;

    float hprev = slots_in[row * 128 + tid];
    float u = 0.f;
    {
        const float* up = upd_part + (((size_t)bb_ * 16) * 3 + ss) * 128 + tid;
#pragma unroll
        for (int c = 0; c < 16; c++) u += up[(size_t)c * 384];
    }
    u_l[tid] = u;
    h_l[tid] = hprev;
    __syncthreads();

    float ir = bih[tid], iz = bih[128 + tid], in_ = bih[256 + tid];
    float hr = bhh[tid], hz = bhh[128 + tid], hn = bhh[256 + tid];
    const float4* wi0 = (const float4*)&Wih[(size_t)tid * 128];
    const float4* wi1 = (const float4*)&Wih[(size_t)(128 + tid) * 128];
    const float4* wi2 = (const float4*)&Wih[(size_t)(256 + tid) * 128];
    const float4* wh0 = (const float4*)&Whh[(size_t)tid * 128];
    const float4* wh1 = (const float4*)&Whh[(size_t)(128 + tid) * 128];
    const float4* wh2 = (const float4*)&Whh[(size_t)(256 + tid) * 128];
#pragma unroll 4
    for (int d4 = 0; d4 < 32; d4++) {
        float u0 = u_l[4 * d4], u1 = u_l[4 * d4 + 1], u2 = u_l[4 * d4 + 2], u3 = u_l[4 * d4 + 3];
        float h0 = h_l[4 * d4], h1 = h_l[4 * d4 + 1], h2 = h_l[4 * d4 + 2], h3 = h_l[4 * d4 + 3];
        float4 w;
        w = wi0[d4]; ir  += u0 * w.x + u1 * w.y + u2 * w.z + u3 * w.w;
        w = wi1[d4]; iz  += u0 * w.x + u1 * w.y + u2 * w.z + u3 * w.w;
        w = wi2[d4]; in_ += u0 * w.x + u1 * w.y + u2 * w.z + u3 * w.w;
        w = wh0[d4]; hr  += h0 * w.x + h1 * w.y + h2 * w.z + h3 * w.w;
        w = wh1[d4]; hz  += h0 * w.x + h1 * w.y + h2 * w.z + h3 * w.w;
        w = wh2[d4]; hn  += h0 * w.x + h1 * w.y + h2 * w.z + h3 * w.w;
    }
    float r = 1.f / (1.f + expf(-(ir + hr)));
    float z = 1.f / (1.f + expf(-(iz + hz)));
    float nn = tanhf(in_ + r * hn);
    float hnew = (1.f - z) * nn + z * hprev;

    float s = hnew, s2 = hnew * hnew;
#pragma unroll
    for (int off = 32; off >= 1; off >>= 1) {
        s += __shfl_down(s, off, 64); s2 += __shfl_down(s2, off, 64);
    }
    if ((tid & 63) == 0) { red[tid >> 6] = s; red[2 + (tid >> 6)] = s2; }
    __syncthreads();
    float S = red[0] + red[1], S2 = red[2] + red[3];
    float m1 = S * (1.f / 128.f);
    float r1 = rsqrtf(S2 * (1.f / 128.f) - m1 * m1 + EPS);
    n_l[tid] = (hnew - m1) * r1 * g_m[tid] + b_m[tid];
    __syncthreads();

    float a0 = b1[tid], a1 = b1[128 + tid];
    const float4* w1a = (const float4*)&W1[(size_t)tid * 128];
    const float4* w1b = (const float4*)&W1[(size_t)(128 + tid) * 128];
#pragma unroll 4
    for (int d4 = 0; d4 < 32; d4++) {
        float x0 = n_l[4 * d4], x1 = n_l[4 * d4 + 1], x2 = n_l[4 * d4 + 2], x3 = n_l[4 * d4 + 3];
        float4 wa = w1a[d4], wb = w1b[d4];
        a0 += x0 * wa.x + x1 * wa.y + x2 * wa.z + x3 * wa.w;
        a1 += x0 * wb.x + x1 * wb.y + x2 * wb.z + x3 * wb.w;
    }
    a0 = 0.5f * a0 * (1.f + erff(a0 * 0.70710678118654752f));
    a1 = 0.5f * a1 * (1.f + erff(a1 * 0.70710678118654752f));
    hid_l[tid] = a0; hid_l[128 + tid] = a1;
    __syncthreads();

    float o = b2[tid];
    const float4* w2r = (const float4*)&W2[(size_t)tid * 256];
#pragma unroll 4
    for (int d4 = 0; d4 < 64; d4++) {
        float4 w = w2r[d4];
        o += hid_l[4 * d4] * w.x + hid_l[4 * d4 + 1] * w.y
           + hid_l[4 * d4 + 2] * w.z + hid_l[4 * d4 + 3] * w.w;
    }
    float snew = hnew + o;
    slots_out[row * 128 + tid] = snew;

    if (write_q) {
        __syncthreads();
        float t = snew, t2 = snew * snew;
#pragma unroll
        for (int off = 32; off >= 1; off >>= 1) {
            t += __shfl_down(t, off, 64); t2 += __shfl_down(t2, off, 64);
        }
        if ((tid & 63) == 0) { red[tid >> 6] = t; red[2 + (tid >> 6)] = t2; }
        __syncthreads();
        float T = red[0] + red[1], T2 = red[2] + red[3];
        float m2 = T * (1.f / 128.f);
        float r2 = rsqrtf(T2 * (1.f / 128.f) - m2 * m2 + EPS);
        n_l[tid] = (snew - m2) * r2 * g_s[tid] + b_s[tid];
        __syncthreads();
        const float4* wr = (const float4*)&Wq[(size_t)tid * 128];
        float a = bq[tid];
#pragma unroll 8
        for (int d4 = 0; d4 < 32; d4++) {
            float4 w = wr[d4];
            a += n_l[4 * d4] * w.x + n_l[4 * d4 + 1] * w.y
               + n_l[4 * d4 + 2] * w.z + n_l[4 * d4 + 3] * w.w;
        }
        q_out[row * 128 + tid] = a;
    }
}

// ============================================================================
extern "C" void kernel_launch(void* const* d_in, const int* in_sizes, int n_in,
                              void* d_out, int out_size, void* d_ws, size_t ws_size,
                              hipStream_t stream)
{
    const float* patch   = (const float*)d_in[0];
    const float* noise   = (const float*)d_in[1];
    const float* slot_mu = (const float*)d_in[2];
    const float* slot_ls = (const float*)d_in[3];
    const float* Wp = (const float*)d_in[4];  const float* bp = (const float*)d_in[5];
    const float* g_in = (const float*)d_in[6]; const float* b_in = (const float*)d_in[7];
    const float* Wq = (const float*)d_in[8];  const float* bq = (const float*)d_in[9];
    const float* Wk = (const float*)d_in[10]; const float* bk = (const float*)d_in[11];
    const float* Wv = (const float*)d_in[12]; const float* bv = (const float*)d_in[13];
    const float* Wih = (const float*)d_in[14]; const float* bih = (const float*)d_in[15];
    const float* Whh = (const float*)d_in[16]; const float* bhh = (const float*)d_in[17];
    const float* g_s = (const float*)d_in[18]; const float* b_s = (const float*)d_in[19];
    const float* W1 = (const float*)d_in[20]; const float* b1 = (const float*)d_in[21];
    const float* W2 = (const float*)d_in[22]; const float* b2 = (const float*)d_in[23];
    const float* g_m = (const float*)d_in[24]; const float* b_m = (const float*)d_in[25];

    // ---- workspace layout (~201.6 MB) ----
    float* kbuf = (float*)d_ws;                                   // 16777216 f32
    float* vbuf = kbuf + 16777216;                                // 16777216 f32
    unsigned short* ln_hi = (unsigned short*)(vbuf + 16777216);   // 16777216 bf16
    unsigned short* ln_lo = ln_hi + 16777216;                     // 16777216 bf16
    unsigned short* w_hi  = ln_lo + 16777216;                     // 57344
    unsigned short* w_lo  = w_hi + 57344;                         // 57344
    unsigned short* wp_hi = w_hi,        * wp_lo = w_lo;
    unsigned short* wk_hi = w_hi + 24576,* wk_lo = w_lo + 24576;
    unsigned short* wv_hi = w_hi + 40960,* wv_lo = w_lo + 40960;
    // slots/q/partials alias the inputs(hi/lo) region — dead after the kv GEMM.
    float* slots = (float*)ln_hi;                                 // 49152 f32
    float* qbuf  = slots + 49152;                                 // 49152 f32
    float* part  = qbuf + 49152;                                  // 786432 f32

    float* out_slots = (float*)d_out;                             // (B,K,H)
    float* out_attn  = (float*)d_out + 49152;                     // (B,K,N)

    split_weights_kernel<<<224, 256, 0, stream>>>(Wp, Wk, Wv, w_hi, w_lo);

    // inputs = LN(patch @ Wp^T + bp) -> hi/lo bf16 planes (LN fused, fp32 math)
    gemm_split_kernel<192, false, true, true><<<1024, 256, 0, stream>>>(
        patch, nullptr, wp_hi, wp_lo, bp, g_in, b_in, nullptr, ln_hi, ln_lo);
    // k = inputs @ Wk^T + bk ; v = inputs @ Wv^T + bv  (fused: A staged once)
    gemm_kv_kernel<<<1024, 256, 0, stream>>>(
        ln_hi, ln_lo, wk_hi, wk_lo, wv_hi, wv_lo, bk, bv, kbuf, vbuf);

    // slots init + LN + q0 (after GEMMs: slots/q alias the inputs region)
    init_lnq_kernel<<<384, 128, 0, stream>>>(noise, slot_mu, slot_ls,
                                             g_s, b_s, Wq, bq, slots, qbuf);

    for (int it = 0; it < 3; it++) {
        attn_kernel<<<dim3(16, 128), 256, 0, stream>>>(
            qbuf, kbuf, vbuf, part, out_attn, it == 2 ? 1 : 0);
        gru_mlp_kernel<<<384, 128, 0, stream>>>(
            slots, part, Wih, bih, Whh, bhh, g_m, b_m, W1, b1, W2, b2,
            g_s, b_s, Wq, bq,
            (it == 2) ? out_slots : slots, qbuf, it == 2 ? 0 : 1);
    }
}

// Round 2
// 468.591 us; speedup vs baseline: 1.0501x; 1.0501x over previous
//
#include <hip/hip_runtime.h>
#include <math.h>

constexpr float EPS = 1e-5f;
constexpr float SCALE = 0.08838834764831845f; // 1/sqrt(128)

using f32x4  = __attribute__((ext_vector_type(4))) float;
using bf16x8 = __attribute__((ext_vector_type(8))) short;
using us8    = __attribute__((ext_vector_type(8))) unsigned short;

__device__ __forceinline__ unsigned short f2b_rne(float f) {
    unsigned int x = __float_as_uint(f);
    return (unsigned short)((x + 0x7fffu + ((x >> 16) & 1u)) >> 16);
}

// XOR-swizzled element offset into a [rows][32]-us tile; k8 = 8-elem col chunk
// (0..3). Breaks the 8-way bank conflict of stride-64B rows down to 2-way.
__device__ __forceinline__ int swz32(int row, int k8) {
    int f = (row & 3) ^ ((row >> 2) & 3);
    return row * 32 + ((k8 ^ f) << 3);
}

// ================= one-time weight split: fp32 -> (hi, lo) bf16 planes =======
// Wp (24576) | Wk (16384) | Wv (16384) packed contiguously.
__global__ __launch_bounds__(256) void split_weights_kernel(
    const float* __restrict__ Wp, const float* __restrict__ Wk,
    const float* __restrict__ Wv, unsigned short* __restrict__ hi,
    unsigned short* __restrict__ lo)
{
    int idx = blockIdx.x * 256 + threadIdx.x; // 57344 total
    float v;
    if (idx < 24576)      v = Wp[idx];
    else if (idx < 40960) v = Wk[idx - 24576];
    else                  v = Wv[idx - 40960];
    unsigned int bits = __float_as_uint(v);
    hi[idx] = (unsigned short)(bits >> 16);
    lo[idx] = f2b_rne(v - __uint_as_float(bits & 0xffff0000u));
}

// ========== mega-fused: X = LN(patch @ Wp^T + bp); k,v = X @ {Wk,Wv}^T =======
// 64-row tile, grid 2048. X (hi/lo bf16, bit-identical to the old global
// intermediate) lives only in LDS -> saves 134 MB of HBM round-trip.
// Split-precision: each fp32 = hi+lo bf16; product = hh+hl+lh (3 MFMAs).
// Reg-prefetch staging (T14), XOR-swizzled LDS. 64 KB LDS -> 2 blocks/CU.
__global__ __launch_bounds__(256, 2) void fused_proj_kv_kernel(
    const float* __restrict__ patch,
    const unsigned short* __restrict__ Wphi, const unsigned short* __restrict__ Wplo,
    const unsigned short* __restrict__ Wkhi, const unsigned short* __restrict__ Wklo,
    const unsigned short* __restrict__ Wvhi, const unsigned short* __restrict__ Wvlo,
    const float* __restrict__ biasp, const float* __restrict__ g_in,
    const float* __restrict__ b_in, const float* __restrict__ biask,
    const float* __restrict__ biasv,
    float* __restrict__ kout, float* __restrict__ vout)
{
    // stg phase 1: Ah[0,2048) Al[2048,4096) Bh[4096,8192) Bl[8192,12288)
    // stg phase 2: Kh[0,4096) Kl[4096,8192) Vh[8192,12288) Vl[12288,16384)
    __shared__ __align__(16) unsigned short stg[16384];            // 32 KB
    __shared__ __align__(16) unsigned short Xh[8192], Xl[8192];    // 2x16 KB

    const int tid  = threadIdx.x;
    const int lane = tid & 63, wave = tid >> 6;
    const int ln15 = lane & 15, quad = lane >> 4;
    const int m0   = blockIdx.x * 64;

    // ---------------- phase 1: X = LN(patch @ Wp^T + bp) ----------------
    const int wrow = wave * 16;                 // 1D: wave owns 16 rows
    f32x4 acc1[8];
#pragma unroll
    for (int nt = 0; nt < 8; nt++)
#pragma unroll
        for (int r = 0; r < 4; r++) acc1[nt][r] = 0.f;

    // prefetch K-step 0
    const int arow = tid >> 2, ak8 = tid & 3;   // A: 1 chunk/thread (64x32)
    const float* aptr = patch + (size_t)(m0 + arow) * 192 + ak8 * 8;
    float4 pa0 = *(const float4*)aptr;
    float4 pa1 = *(const float4*)(aptr + 4);
    us8 pbh[2], pbl[2];                          // B: 2 chunks/thread (128x32)
    int boff[2];
#pragma unroll
    for (int i = 0; i < 2; i++) {
        int c = tid + 256 * i;
        boff[i] = (c >> 2) * 192 + (c & 3) * 8;
        pbh[i] = *(const us8*)(Wphi + boff[i]);
        pbl[i] = *(const us8*)(Wplo + boff[i]);
    }

    const int ea = swz32(wrow + ln15, quad);     // frag offsets (kk-invariant)

    for (int kk = 0; kk < 192; kk += 32) {
        // store prefetched tile (split A fp32 -> hi/lo while writing)
        {
            float va[8] = {pa0.x, pa0.y, pa0.z, pa0.w, pa1.x, pa1.y, pa1.z, pa1.w};
            us8 h, l;
#pragma unroll
            for (int j = 0; j < 8; j++) {
                unsigned int bits = __float_as_uint(va[j]);
                h[j] = (unsigned short)(bits >> 16);
                l[j] = f2b_rne(va[j] - __uint_as_float(bits & 0xffff0000u));
            }
            int e = swz32(arow, ak8);
            *(us8*)&stg[e]        = h;
            *(us8*)&stg[2048 + e] = l;
        }
#pragma unroll
        for (int i = 0; i < 2; i++) {
            int c = tid + 256 * i;
            int e = swz32(c >> 2, c & 3);
            *(us8*)&stg[4096 + e] = pbh[i];
            *(us8*)&stg[8192 + e] = pbl[i];
        }
        __syncthreads();

        // prefetch K-step kk+32 (hides global latency under MFMAs)
        int kn = kk + 32;
        if (kn < 192) {
            pa0 = *(const float4*)(aptr + kn);
            pa1 = *(const float4*)(aptr + kn + 4);
#pragma unroll
            for (int i = 0; i < 2; i++) {
                pbh[i] = *(const us8*)(Wphi + boff[i] + kn);
                pbl[i] = *(const us8*)(Wplo + boff[i] + kn);
            }
        }

        bf16x8 ah = *(const bf16x8*)&stg[ea];
        bf16x8 al = *(const bf16x8*)&stg[2048 + ea];
#pragma unroll
        for (int nt = 0; nt < 8; nt++) {
            int eb = swz32(nt * 16 + ln15, quad);
            bf16x8 bh = *(const bf16x8*)&stg[4096 + eb];
            bf16x8 bl = *(const bf16x8*)&stg[8192 + eb];
            acc1[nt] = __builtin_amdgcn_mfma_f32_16x16x32_bf16(ah, bh, acc1[nt], 0, 0, 0);
            acc1[nt] = __builtin_amdgcn_mfma_f32_16x16x32_bf16(ah, bl, acc1[nt], 0, 0, 0);
            acc1[nt] = __builtin_amdgcn_mfma_f32_16x16x32_bf16(al, bh, acc1[nt], 0, 0, 0);
        }
        __syncthreads();
    }

    // phase-2 weight prefetch issued NOW so its latency hides under the LN
    // epilogue. 8 chunks/thread; plane index i>>1 is compile-time constant.
    us8 pw[8];
#pragma unroll
    for (int i = 0; i < 8; i++) {
        const unsigned short* pl = (i >> 1) == 0 ? Wkhi
                                 : (i >> 1) == 1 ? Wklo
                                 : (i >> 1) == 2 ? Wvhi : Wvlo;
        int c = tid + (i & 1) * 256;
        pw[i] = *(const us8*)(pl + (size_t)(c >> 2) * 128 + (c & 3) * 8);
    }

    // ---- LN epilogue -> X hi/lo into LDS (bit-identical to old global path)
    {
        float bb[8], gg[8], be[8];
#pragma unroll
        for (int nt = 0; nt < 8; nt++) {
            int col = nt * 16 + ln15;
            bb[nt] = biasp[col]; gg[nt] = g_in[col]; be[nt] = b_in[col];
        }
#pragma unroll
        for (int nt = 0; nt < 8; nt++)
#pragma unroll
            for (int r = 0; r < 4; r++) acc1[nt][r] += bb[nt];

        float mu[4], rs[4];
#pragma unroll
        for (int r = 0; r < 4; r++) {
            float s = 0.f, s2 = 0.f;
#pragma unroll
            for (int nt = 0; nt < 8; nt++) {
                float v = acc1[nt][r];
                s += v; s2 += v * v;
            }
#pragma unroll
            for (int off = 1; off < 16; off <<= 1) {
                s  += __shfl_xor(s,  off, 64);
                s2 += __shfl_xor(s2, off, 64);
            }
            float m = s * (1.f / 128.f);
            mu[r] = m;
            rs[r] = rsqrtf(s2 * (1.f / 128.f) - m * m + EPS);
        }
#pragma unroll
        for (int nt = 0; nt < 8; nt++)
#pragma unroll
            for (int r = 0; r < 4; r++) {
                float v = (acc1[nt][r] - mu[r]) * rs[r] * gg[nt] + be[nt];
                int row = wrow + quad * 4 + r, col = nt * 16 + ln15;
                int xi = (row * 128 + col) ^ ((row & 7) << 3);
                unsigned int bits = __float_as_uint(v);
                Xh[xi] = (unsigned short)(bits >> 16);
                Xl[xi] = f2b_rne(v - __uint_as_float(bits & 0xffff0000u));
            }
    }

    // store phase-2 K-step 0 weight tiles (stg reads all done at last barrier)
#pragma unroll
    for (int i = 0; i < 8; i++) {
        int c = tid + (i & 1) * 256;
        int e = (i >> 1) * 4096 + swz32(c >> 2, c & 3);
        *(us8*)&stg[e] = pw[i];
    }
    __syncthreads();

    // ---------------- phase 2: k,v = X @ {Wk,Wv}^T -----------------------
    // 2x2 wave grid: wave owns 32 rows x 64 cols (keeps MFMA:ds_read balanced)
    const int R  = (wave & 1) * 32;
    const int Cb = (wave >> 1) * 64;
    const int xorx = (ln15 & 7) << 3;

    f32x4 acck[2][4], accv[2][4];
#pragma unroll
    for (int mt = 0; mt < 2; mt++)
#pragma unroll
        for (int nt = 0; nt < 4; nt++)
#pragma unroll
            for (int r = 0; r < 4; r++) { acck[mt][nt][r] = 0.f; accv[mt][nt][r] = 0.f; }

    for (int kk = 0; kk < 128; kk += 32) {
        if (kk) {
#pragma unroll
            for (int i = 0; i < 8; i++) {
                int c = tid + (i & 1) * 256;
                int e = (i >> 1) * 4096 + swz32(c >> 2, c & 3);
                *(us8*)&stg[e] = pw[i];
            }
            __syncthreads();
        }
        int kn = kk + 32;
        if (kn < 128) {
#pragma unroll
            for (int i = 0; i < 8; i++) {
                const unsigned short* pl = (i >> 1) == 0 ? Wkhi
                                         : (i >> 1) == 1 ? Wklo
                                         : (i >> 1) == 2 ? Wvhi : Wvlo;
                int c = tid + (i & 1) * 256;
                pw[i] = *(const us8*)(pl + (size_t)(c >> 2) * 128 + (c & 3) * 8 + kn);
            }
        }

        bf16x8 xh[2], xl[2];
#pragma unroll
        for (int mt = 0; mt < 2; mt++) {
            int row = R + mt * 16 + ln15;
            int ei = (row * 128 + kk + quad * 8) ^ xorx;
            xh[mt] = *(const bf16x8*)&Xh[ei];
            xl[mt] = *(const bf16x8*)&Xl[ei];
        }
#pragma unroll
        for (int nt = 0; nt < 4; nt++) {
            int eb = swz32(Cb + nt * 16 + ln15, quad);
            bf16x8 kh = *(const bf16x8*)&stg[eb];
            bf16x8 kl = *(const bf16x8*)&stg[4096 + eb];
            bf16x8 vh = *(const bf16x8*)&stg[8192 + eb];
            bf16x8 vl = *(const bf16x8*)&stg[12288 + eb];
#pragma unroll
            for (int mt = 0; mt < 2; mt++) {
                acck[mt][nt] = __builtin_amdgcn_mfma_f32_16x16x32_bf16(xh[mt], kh, acck[mt][nt], 0, 0, 0);
                acck[mt][nt] = __builtin_amdgcn_mfma_f32_16x16x32_bf16(xh[mt], kl, acck[mt][nt], 0, 0, 0);
                acck[mt][nt] = __builtin_amdgcn_mfma_f32_16x16x32_bf16(xl[mt], kh, acck[mt][nt], 0, 0, 0);
                accv[mt][nt] = __builtin_amdgcn_mfma_f32_16x16x32_bf16(xh[mt], vh, accv[mt][nt], 0, 0, 0);
                accv[mt][nt] = __builtin_amdgcn_mfma_f32_16x16x32_bf16(xh[mt], vl, accv[mt][nt], 0, 0, 0);
                accv[mt][nt] = __builtin_amdgcn_mfma_f32_16x16x32_bf16(xl[mt], vh, accv[mt][nt], 0, 0, 0);
            }
        }
        if (kn < 128) __syncthreads();
    }

    // ---- epilogue: bias -> store k, v (fp32) ----
    float bbk[4], bbv[4];
#pragma unroll
    for (int nt = 0; nt < 4; nt++) {
        int col = Cb + nt * 16 + ln15;
        bbk[nt] = biask[col];
        bbv[nt] = biasv[col];
    }
#pragma unroll
    for (int mt = 0; mt < 2; mt++)
#pragma unroll
        for (int nt = 0; nt < 4; nt++)
#pragma unroll
            for (int r = 0; r < 4; r++) {
                size_t o = (size_t)(m0 + R + mt * 16 + quad * 4 + r) * 128
                         + Cb + nt * 16 + ln15;
                kout[o] = acck[mt][nt][r] + bbk[nt];
                vout[o] = accv[mt][nt][r] + bbv[nt];
            }
}

// =================== init slots + LN + q (one block per slot row) ============
__global__ __launch_bounds__(128) void init_lnq_kernel(
    const float* __restrict__ noise, const float* __restrict__ smu,
    const float* __restrict__ sls, const float* __restrict__ g_s,
    const float* __restrict__ b_s, const float* __restrict__ Wq,
    const float* __restrict__ bq, float* __restrict__ slots,
    float* __restrict__ q)
{
    __shared__ float s_l[128];
    __shared__ float red[4];
    const int row = blockIdx.x, tid = threadIdx.x;
    const int k = row % 3;
    float x = smu[k * 128 + tid] + expf(sls[k * 128 + tid]) * noise[row * 128 + tid];
    slots[row * 128 + tid] = x;

    float s = x, s2 = x * x;
#pragma unroll
    for (int off = 32; off >= 1; off >>= 1) {
        s += __shfl_down(s, off, 64); s2 += __shfl_down(s2, off, 64);
    }
    if ((tid & 63) == 0) { red[tid >> 6] = s; red[2 + (tid >> 6)] = s2; }
    __syncthreads();
    float S = red[0] + red[1], S2 = red[2] + red[3];
    float m = S * (1.f / 128.f);
    float r = rsqrtf(S2 * (1.f / 128.f) - m * m + EPS);
    s_l[tid] = (x - m) * r * g_s[tid] + b_s[tid];
    __syncthreads();

    const float4* wr = (const float4*)&Wq[(size_t)tid * 128];
    float a = bq[tid];
#pragma unroll 8
    for (int d4 = 0; d4 < 32; d4++) {
        float4 w = wr[d4];
        a += s_l[4 * d4] * w.x + s_l[4 * d4 + 1] * w.y
           + s_l[4 * d4 + 2] * w.z + s_l[4 * d4 + 3] * w.w;
    }
    q[row * 128 + tid] = a;
}

// ============ fused attention: logits -> softmax(K=3) -> partial updates =====
// fp32 k/v; per-chunk partial outputs (no atomics/memset).
__global__ __launch_bounds__(256) void attn_kernel(
    const float* __restrict__ q, const float* __restrict__ kbuf,
    const float* __restrict__ vbuf, float* __restrict__ upd_part,
    float* __restrict__ attn_out, int write_attn)
{
    __shared__ float q_l[3][128];
    __shared__ __align__(16) float kv[64][132];
    __shared__ float lg[3][64];
    __shared__ float w_l[3][64];
    const int b = blockIdx.y, chunk = blockIdx.x, n0 = chunk * 64, tid = threadIdx.x;

    for (int idx = tid; idx < 384; idx += 256)
        q_l[idx >> 7][idx & 127] = q[b * 384 + idx];

    const float4* kg = (const float4*)(kbuf + ((size_t)b * 1024 + n0) * 128);
    for (int idx = tid; idx < 2048; idx += 256) {
        int n = idx >> 5, c = (idx & 31) * 4;
        *(float4*)&kv[n][c] = kg[idx];
    }
    __syncthreads();

    { // logits: thread = (token n, quarter q4); all 256 threads active
        int n = tid >> 2, q4 = tid & 3;
        const float* kr = &kv[n][q4 * 32];
        const float* q0 = &q_l[0][q4 * 32];
        const float* q1 = &q_l[1][q4 * 32];
        const float* q2 = &q_l[2][q4 * 32];
        float p0 = 0.f, p1 = 0.f, p2 = 0.f;
#pragma unroll 8
        for (int i = 0; i < 32; i++) {
            float vv = kr[i];
            p0 += q0[i] * vv; p1 += q1[i] * vv; p2 += q2[i] * vv;
        }
        p0 += __shfl_xor(p0, 1, 64); p0 += __shfl_xor(p0, 2, 64);
        p1 += __shfl_xor(p1, 1, 64); p1 += __shfl_xor(p1, 2, 64);
        p2 += __shfl_xor(p2, 1, 64); p2 += __shfl_xor(p2, 2, 64);
        if (q4 == 0) {
            lg[0][n] = p0 * SCALE; lg[1][n] = p1 * SCALE; lg[2][n] = p2 * SCALE;
        }
    }
    __syncthreads();

    if (tid < 64) { // softmax over the 3 slots for token n=tid
        float l0 = lg[0][tid], l1 = lg[1][tid], l2 = lg[2][tid];
        float m = fmaxf(l0, fmaxf(l1, l2));
        float e0 = expf(l0 - m), e1 = expf(l1 - m), e2 = expf(l2 - m);
        float inv = 1.f / (e0 + e1 + e2);
        w_l[0][tid] = e0 * inv; w_l[1][tid] = e1 * inv; w_l[2][tid] = e2 * inv;
        if (write_attn) {
            attn_out[b * 3072 + n0 + tid]        = e0 * inv;
            attn_out[b * 3072 + 1024 + n0 + tid] = e1 * inv;
            attn_out[b * 3072 + 2048 + n0 + tid] = e2 * inv;
        }
    }
    const float4* vg = (const float4*)(vbuf + ((size_t)b * 1024 + n0) * 128);
    for (int idx = tid; idx < 2048; idx += 256) {
        int n = idx >> 5, c = (idx & 31) * 4;
        *(float4*)&kv[n][c] = vg[idx];
    }
    __syncthreads();

    if (tid < 128) {
        float p0 = 0.f, p1 = 0.f, p2 = 0.f;
#pragma unroll 8
        for (int n = 0; n < 64; n++) {
            float vv = kv[n][tid];
            p0 += w_l[0][n] * vv; p1 += w_l[1][n] * vv; p2 += w_l[2][n] * vv;
        }
        size_t base = (((size_t)b * 16 + chunk) * 3) * 128 + tid;
        upd_part[base]       = p0;
        upd_part[base + 128] = p1;
        upd_part[base + 256] = p2;
    }
}

// ====== fused GRU cell + LN + MLP residual + (LN_s + q for next iter) ========
__global__ __launch_bounds__(128) void gru_mlp_kernel(
    const float* __restrict__ slots_in, const float* __restrict__ upd_part,
    const float* __restrict__ Wih, const float* __restrict__ bih,
    const float* __restrict__ Whh, const float* __restrict__ bhh,
    const float* __restrict__ g_m, const float* __restrict__ b_m,
    const float* __restrict__ W1, const float* __restrict__ b1,
    const float* __restrict__ W2, const float* __restrict__ b2,
    const float* __restrict__ g_s, const float* __restrict__ b_s,
    const float* __restrict__ Wq, const float* __restrict__ bq,
    float* __restrict__ slots_out, float* __restrict__ q_out, int write_q)
{
    __shared__ float u_l[128], h_l[128], n_l[128], hid_l[256];
    __shared__ float red[4];
    const int row = blockIdx.x, tid = threadIdx.x;
    const int bb_ = row / 3, ss = row - bb_ * 3;

    float hprev = slots_in[row * 128 + tid];
    float u = 0.f;
    {
        const float* up = upd_part + (((size_t)bb_ * 16) * 3 + ss) * 128 + tid;
#pragma unroll
        for (int c = 0; c < 16; c++) u += up[(size_t)c * 384];
    }
    u_l[tid] = u;
    h_l[tid] = hprev;
    __syncthreads();

    float ir = bih[tid], iz = bih[128 + tid], in_ = bih[256 + tid];
    float hr = bhh[tid], hz = bhh[128 + tid], hn = bhh[256 + tid];
    const float4* wi0 = (const float4*)&Wih[(size_t)tid * 128];
    const float4* wi1 = (const float4*)&Wih[(size_t)(128 + tid) * 128];
    const float4* wi2 = (const float4*)&Wih[(size_t)(256 + tid) * 128];
    const float4* wh0 = (const float4*)&Whh[(size_t)tid * 128];
    const float4* wh1 = (const float4*)&Whh[(size_t)(128 + tid) * 128];
    const float4* wh2 = (const float4*)&Whh[(size_t)(256 + tid) * 128];
#pragma unroll 4
    for (int d4 = 0; d4 < 32; d4++) {
        float u0 = u_l[4 * d4], u1 = u_l[4 * d4 + 1], u2 = u_l[4 * d4 + 2], u3 = u_l[4 * d4 + 3];
        float h0 = h_l[4 * d4], h1 = h_l[4 * d4 + 1], h2 = h_l[4 * d4 + 2], h3 = h_l[4 * d4 + 3];
        float4 w;
        w = wi0[d4]; ir  += u0 * w.x + u1 * w.y + u2 * w.z + u3 * w.w;
        w = wi1[d4]; iz  += u0 * w.x + u1 * w.y + u2 * w.z + u3 * w.w;
        w = wi2[d4]; in_ += u0 * w.x + u1 * w.y + u2 * w.z + u3 * w.w;
        w = wh0[d4]; hr  += h0 * w.x + h1 * w.y + h2 * w.z + h3 * w.w;
        w = wh1[d4]; hz  += h0 * w.x + h1 * w.y + h2 * w.z + h3 * w.w;
        w = wh2[d4]; hn  += h0 * w.x + h1 * w.y + h2 * w.z + h3 * w.w;
    }
    float r = 1.f / (1.f + expf(-(ir + hr)));
    float z = 1.f / (1.f + expf(-(iz + hz)));
    float nn = tanhf(in_ + r * hn);
    float hnew = (1.f - z) * nn + z * hprev;

    float s = hnew, s2 = hnew * hnew;
#pragma unroll
    for (int off = 32; off >= 1; off >>= 1) {
        s += __shfl_down(s, off, 64); s2 += __shfl_down(s2, off, 64);
    }
    if ((tid & 63) == 0) { red[tid >> 6] = s; red[2 + (tid >> 6)] = s2; }
    __syncthreads();
    float S = red[0] + red[1], S2 = red[2] + red[3];
    float m1 = S * (1.f / 128.f);
    float r1 = rsqrtf(S2 * (1.f / 128.f) - m1 * m1 + EPS);
    n_l[tid] = (hnew - m1) * r1 * g_m[tid] + b_m[tid];
    __syncthreads();

    float a0 = b1[tid], a1 = b1[128 + tid];
    const float4* w1a = (const float4*)&W1[(size_t)tid * 128];
    const float4* w1b = (const float4*)&W1[(size_t)(128 + tid) * 128];
#pragma unroll 4
    for (int d4 = 0; d4 < 32; d4++) {
        float x0 = n_l[4 * d4], x1 = n_l[4 * d4 + 1], x2 = n_l[4 * d4 + 2], x3 = n_l[4 * d4 + 3];
        float4 wa = w1a[d4], wb = w1b[d4];
        a0 += x0 * wa.x + x1 * wa.y + x2 * wa.z + x3 * wa.w;
        a1 += x0 * wb.x + x1 * wb.y + x2 * wb.z + x3 * wb.w;
    }
    a0 = 0.5f * a0 * (1.f + erff(a0 * 0.70710678118654752f));
    a1 = 0.5f * a1 * (1.f + erff(a1 * 0.70710678118654752f));
    hid_l[tid] = a0; hid_l[128 + tid] = a1;
    __syncthreads();

    float o = b2[tid];
    const float4* w2r = (const float4*)&W2[(size_t)tid * 256];
#pragma unroll 4
    for (int d4 = 0; d4 < 64; d4++) {
        float4 w = w2r[d4];
        o += hid_l[4 * d4] * w.x + hid_l[4 * d4 + 1] * w.y
           + hid_l[4 * d4 + 2] * w.z + hid_l[4 * d4 + 3] * w.w;
    }
    float snew = hnew + o;
    slots_out[row * 128 + tid] = snew;

    if (write_q) {
        __syncthreads();
        float t = snew, t2 = snew * snew;
#pragma unroll
        for (int off = 32; off >= 1; off >>= 1) {
            t += __shfl_down(t, off, 64); t2 += __shfl_down(t2, off, 64);
        }
        if ((tid & 63) == 0) { red[tid >> 6] = t; red[2 + (tid >> 6)] = t2; }
        __syncthreads();
        float T = red[0] + red[1], T2 = red[2] + red[3];
        float m2 = T * (1.f / 128.f);
        float r2 = rsqrtf(T2 * (1.f / 128.f) - m2 * m2 + EPS);
        n_l[tid] = (snew - m2) * r2 * g_s[tid] + b_s[tid];
        __syncthreads();
        const float4* wr = (const float4*)&Wq[(size_t)tid * 128];
        float a = bq[tid];
#pragma unroll 8
        for (int d4 = 0; d4 < 32; d4++) {
            float4 w = wr[d4];
            a += n_l[4 * d4] * w.x + n_l[4 * d4 + 1] * w.y
               + n_l[4 * d4 + 2] * w.z + n_l[4 * d4 + 3] * w.w;
        }
        q_out[row * 128 + tid] = a;
    }
}

// ============================================================================
extern "C" void kernel_launch(void* const* d_in, const int* in_sizes, int n_in,
                              void* d_out, int out_size, void* d_ws, size_t ws_size,
                              hipStream_t stream)
{
    const float* patch   = (const float*)d_in[0];
    const float* noise   = (const float*)d_in[1];
    const float* slot_mu = (const float*)d_in[2];
    const float* slot_ls = (const float*)d_in[3];
    const float* Wp = (const float*)d_in[4];  const float* bp = (const float*)d_in[5];
    const float* g_in = (const float*)d_in[6]; const float* b_in = (const float*)d_in[7];
    const float* Wq = (const float*)d_in[8];  const float* bq = (const float*)d_in[9];
    const float* Wk = (const float*)d_in[10]; const float* bk = (const float*)d_in[11];
    const float* Wv = (const float*)d_in[12]; const float* bv = (const float*)d_in[13];
    const float* Wih = (const float*)d_in[14]; const float* bih = (const float*)d_in[15];
    const float* Whh = (const float*)d_in[16]; const float* bhh = (const float*)d_in[17];
    const float* g_s = (const float*)d_in[18]; const float* b_s = (const float*)d_in[19];
    const float* W1 = (const float*)d_in[20]; const float* b1 = (const float*)d_in[21];
    const float* W2 = (const float*)d_in[22]; const float* b2 = (const float*)d_in[23];
    const float* g_m = (const float*)d_in[24]; const float* b_m = (const float*)d_in[25];

    // ---- workspace layout (~138 MB; no more LN-intermediate planes) ----
    float* kbuf = (float*)d_ws;                                   // 16777216 f32
    float* vbuf = kbuf + 16777216;                                // 16777216 f32
    unsigned short* w_hi = (unsigned short*)(vbuf + 16777216);    // 57344
    unsigned short* w_lo = w_hi + 57344;                          // 57344
    unsigned short* wp_hi = w_hi,        * wp_lo = w_lo;
    unsigned short* wk_hi = w_hi + 24576,* wk_lo = w_lo + 24576;
    unsigned short* wv_hi = w_hi + 40960,* wv_lo = w_lo + 40960;
    float* slots = (float*)(w_lo + 57344);                        // 49152 f32
    float* qbuf  = slots + 49152;                                 // 49152 f32
    float* part  = qbuf + 49152;                                  // 786432 f32

    float* out_slots = (float*)d_out;                             // (B,K,H)
    float* out_attn  = (float*)d_out + 49152;                     // (B,K,N)

    split_weights_kernel<<<224, 256, 0, stream>>>(Wp, Wk, Wv, w_hi, w_lo);

    // X = LN(patch @ Wp^T + bp) kept in LDS; k,v written directly.
    fused_proj_kv_kernel<<<2048, 256, 0, stream>>>(
        patch, wp_hi, wp_lo, wk_hi, wk_lo, wv_hi, wv_lo,
        bp, g_in, b_in, bk, bv, kbuf, vbuf);

    // slots init + LN + q0
    init_lnq_kernel<<<384, 128, 0, stream>>>(noise, slot_mu, slot_ls,
                                             g_s, b_s, Wq, bq, slots, qbuf);

    for (int it = 0; it < 3; it++) {
        attn_kernel<<<dim3(16, 128), 256, 0, stream>>>(
            qbuf, kbuf, vbuf, part, out_attn, it == 2 ? 1 : 0);
        gru_mlp_kernel<<<384, 128, 0, stream>>>(
            slots, part, Wih, bih, Whh, bhh, g_m, b_m, W1, b1, W2, b2,
            g_s, b_s, Wq, bq,
            (it == 2) ? out_slots : slots, qbuf, it == 2 ? 0 : 1);
    }
}

// Round 3
// 379.457 us; speedup vs baseline: 1.2968x; 1.2349x over previous
//
#include <hip/hip_runtime.h>
#include <math.h>

constexpr float EPS = 1e-5f;
constexpr float SCALE = 0.08838834764831845f; // 1/sqrt(128)

using f32x4  = __attribute__((ext_vector_type(4))) float;
using bf16x8 = __attribute__((ext_vector_type(8))) short;
using us8    = __attribute__((ext_vector_type(8))) unsigned short;

__device__ __forceinline__ unsigned short f2b_rne(float f) {
    unsigned int x = __float_as_uint(f);
    return (unsigned short)((x + 0x7fffu + ((x >> 16) & 1u)) >> 16);
}

// XOR-swizzled element offset into a [rows][32]-us tile; k8 = 8-elem col chunk.
__device__ __forceinline__ int swz32(int row, int k8) {
    int f = (row & 3) ^ ((row >> 2) & 3);
    return row * 32 + ((k8 ^ f) << 3);
}

// ================= one-time weight split: fp32 -> (hi, lo) bf16 planes =======
__global__ __launch_bounds__(256) void split_weights_kernel(
    const float* __restrict__ Wp, const float* __restrict__ Wk,
    const float* __restrict__ Wv, unsigned short* __restrict__ hi,
    unsigned short* __restrict__ lo)
{
    int idx = blockIdx.x * 256 + threadIdx.x; // 57344 total
    float v;
    if (idx < 24576)      v = Wp[idx];
    else if (idx < 40960) v = Wk[idx - 24576];
    else                  v = Wv[idx - 40960];
    unsigned int bits = __float_as_uint(v);
    hi[idx] = (unsigned short)(bits >> 16);
    lo[idx] = f2b_rne(v - __uint_as_float(bits & 0xffff0000u));
}

// ========== one-time pack: W[out][K] -> WT4[K/4][out] float4 (coalesced) =====
// Layout in out[]: WihT4[0,12288) WhhT4[12288,24576) W1T4[24576,32768)
//                  W2T4[32768,40960) WqT4[40960,45056)
__global__ __launch_bounds__(256) void pack_weights_kernel(
    const float* __restrict__ Wih, const float* __restrict__ Whh,
    const float* __restrict__ W1, const float* __restrict__ W2,
    const float* __restrict__ Wq, float4* __restrict__ out)
{
    int idx = blockIdx.x * 256 + threadIdx.x; // 45056 total
    const float* src; int OUT, base, K;
    if (idx < 12288)      { src = Wih; OUT = 384; base = 0;     K = 128; }
    else if (idx < 24576) { src = Whh; OUT = 384; base = 12288; K = 128; }
    else if (idx < 32768) { src = W1;  OUT = 256; base = 24576; K = 128; }
    else if (idx < 40960) { src = W2;  OUT = 128; base = 32768; K = 256; }
    else                  { src = Wq;  OUT = 128; base = 40960; K = 128; }
    int li = idx - base;
    int kq = li / OUT, t = li - kq * OUT;
    float4 v;
    v.x = src[(size_t)t * K + 4 * kq];
    v.y = src[(size_t)t * K + 4 * kq + 1];
    v.z = src[(size_t)t * K + 4 * kq + 2];
    v.w = src[(size_t)t * K + 4 * kq + 3];
    out[idx] = v;
}

// ========== mega-fused: X = LN(patch @ Wp^T + bp); k,v = X @ {Wk,Wv}^T =======
// 48 KB LDS (X aliases phase-1 staging; phase 2 runs k-pass then v-pass with a
// 16 KB weight buffer) -> 3 blocks/CU. Split-precision 3-MFMA scheme.
__global__ __launch_bounds__(256, 3) void fused_proj_kv_kernel(
    const float* __restrict__ patch,
    const unsigned short* __restrict__ Wphi, const unsigned short* __restrict__ Wplo,
    const unsigned short* __restrict__ Wkhi, const unsigned short* __restrict__ Wklo,
    const unsigned short* __restrict__ Wvhi, const unsigned short* __restrict__ Wvlo,
    const float* __restrict__ biasp, const float* __restrict__ g_in,
    const float* __restrict__ b_in, const float* __restrict__ biask,
    const float* __restrict__ biasv,
    float* __restrict__ kout, float* __restrict__ vout)
{
    // mem layout (48 KB):
    //  phase 1: Ah[0,2048) Al[2048,4096) Bh[4096,8192) Bl[8192,12288)
    //  X (after phase 1): Xh[0,8192) Xl[8192,16384)
    //  phase 2 weights: Wh[16384,20480) Wl[20480,24576)
    __shared__ __align__(16) unsigned short mem[24576];

    const int tid  = threadIdx.x;
    const int lane = tid & 63, wave = tid >> 6;
    const int ln15 = lane & 15, quad = lane >> 4;
    const int m0   = blockIdx.x * 64;

    // ---------------- phase 1: X = LN(patch @ Wp^T + bp) ----------------
    const int wrow = wave * 16;                 // wave owns 16 rows
    f32x4 acc1[8];
#pragma unroll
    for (int nt = 0; nt < 8; nt++)
#pragma unroll
        for (int r = 0; r < 4; r++) acc1[nt][r] = 0.f;

    const int arow = tid >> 2, ak8 = tid & 3;   // A: 1 chunk/thread (64x32)
    const float* aptr = patch + (size_t)(m0 + arow) * 192 + ak8 * 8;
    float4 pa0 = *(const float4*)aptr;
    float4 pa1 = *(const float4*)(aptr + 4);
    us8 pbh[2], pbl[2];                          // B: 2 chunks/thread (128x32)
    int boff[2];
#pragma unroll
    for (int i = 0; i < 2; i++) {
        int c = tid + 256 * i;
        boff[i] = (c >> 2) * 192 + (c & 3) * 8;
        pbh[i] = *(const us8*)(Wphi + boff[i]);
        pbl[i] = *(const us8*)(Wplo + boff[i]);
    }

    const int ea = swz32(wrow + ln15, quad);

    for (int kk = 0; kk < 192; kk += 32) {
        {
            float va[8] = {pa0.x, pa0.y, pa0.z, pa0.w, pa1.x, pa1.y, pa1.z, pa1.w};
            us8 h, l;
#pragma unroll
            for (int j = 0; j < 8; j++) {
                unsigned int bits = __float_as_uint(va[j]);
                h[j] = (unsigned short)(bits >> 16);
                l[j] = f2b_rne(va[j] - __uint_as_float(bits & 0xffff0000u));
            }
            int e = swz32(arow, ak8);
            *(us8*)&mem[e]        = h;
            *(us8*)&mem[2048 + e] = l;
        }
#pragma unroll
        for (int i = 0; i < 2; i++) {
            int c = tid + 256 * i;
            int e = swz32(c >> 2, c & 3);
            *(us8*)&mem[4096 + e] = pbh[i];
            *(us8*)&mem[8192 + e] = pbl[i];
        }
        __syncthreads();

        int kn = kk + 32;
        if (kn < 192) {
            pa0 = *(const float4*)(aptr + kn);
            pa1 = *(const float4*)(aptr + kn + 4);
#pragma unroll
            for (int i = 0; i < 2; i++) {
                pbh[i] = *(const us8*)(Wphi + boff[i] + kn);
                pbl[i] = *(const us8*)(Wplo + boff[i] + kn);
            }
        }

        bf16x8 ah = *(const bf16x8*)&mem[ea];
        bf16x8 al = *(const bf16x8*)&mem[2048 + ea];
#pragma unroll
        for (int nt = 0; nt < 8; nt++) {
            int eb = swz32(nt * 16 + ln15, quad);
            bf16x8 bh = *(const bf16x8*)&mem[4096 + eb];
            bf16x8 bl = *(const bf16x8*)&mem[8192 + eb];
            acc1[nt] = __builtin_amdgcn_mfma_f32_16x16x32_bf16(ah, bh, acc1[nt], 0, 0, 0);
            acc1[nt] = __builtin_amdgcn_mfma_f32_16x16x32_bf16(ah, bl, acc1[nt], 0, 0, 0);
            acc1[nt] = __builtin_amdgcn_mfma_f32_16x16x32_bf16(al, bh, acc1[nt], 0, 0, 0);
        }
        __syncthreads();
    }

    // prefetch phase-2 step-0 weights (k-pass, kk=0): latency hides under LN
    us8 pw[4];
#pragma unroll
    for (int i = 0; i < 4; i++) {
        const unsigned short* pl = (i >> 1) ? Wklo : Wkhi;
        int c = tid + (i & 1) * 256;
        pw[i] = *(const us8*)(pl + (size_t)(c >> 2) * 128 + (c & 3) * 8);
    }

    // ---- LN epilogue -> X hi/lo into LDS (aliases dead phase-1 staging) ----
    {
        float bb[8], gg[8], be[8];
#pragma unroll
        for (int nt = 0; nt < 8; nt++) {
            int col = nt * 16 + ln15;
            bb[nt] = biasp[col]; gg[nt] = g_in[col]; be[nt] = b_in[col];
        }
#pragma unroll
        for (int nt = 0; nt < 8; nt++)
#pragma unroll
            for (int r = 0; r < 4; r++) acc1[nt][r] += bb[nt];

        float mu[4], rs[4];
#pragma unroll
        for (int r = 0; r < 4; r++) {
            float s = 0.f, s2 = 0.f;
#pragma unroll
            for (int nt = 0; nt < 8; nt++) {
                float v = acc1[nt][r];
                s += v; s2 += v * v;
            }
#pragma unroll
            for (int off = 1; off < 16; off <<= 1) {
                s  += __shfl_xor(s,  off, 64);
                s2 += __shfl_xor(s2, off, 64);
            }
            float m = s * (1.f / 128.f);
            mu[r] = m;
            rs[r] = rsqrtf(s2 * (1.f / 128.f) - m * m + EPS);
        }
#pragma unroll
        for (int nt = 0; nt < 8; nt++)
#pragma unroll
            for (int r = 0; r < 4; r++) {
                float v = (acc1[nt][r] - mu[r]) * rs[r] * gg[nt] + be[nt];
                int row = wrow + quad * 4 + r, col = nt * 16 + ln15;
                int xi = (row * 128 + col) ^ ((row & 7) << 3);
                unsigned int bits = __float_as_uint(v);
                mem[xi]        = (unsigned short)(bits >> 16);
                mem[8192 + xi] = f2b_rne(v - __uint_as_float(bits & 0xffff0000u));
            }
    }

    // ---------------- phase 2: k-pass (s=0..3) then v-pass (s=4..7) -------
    const int R  = (wave & 1) * 32;
    const int Cb = (wave >> 1) * 64;
    const int xorx = (ln15 & 7) << 3;

    float bbk[4], bbv[4];
#pragma unroll
    for (int nt = 0; nt < 4; nt++) {
        int col = Cb + nt * 16 + ln15;
        bbk[nt] = biask[col];
        bbv[nt] = biasv[col];
    }

    f32x4 acc[2][4];
#pragma unroll
    for (int mt = 0; mt < 2; mt++)
#pragma unroll
        for (int nt = 0; nt < 4; nt++)
#pragma unroll
            for (int r = 0; r < 4; r++) acc[mt][nt][r] = 0.f;

    for (int s = 0; s < 8; s++) {
        // store staged weight tile (loaded in previous iteration / prologue)
#pragma unroll
        for (int i = 0; i < 4; i++) {
            int c = tid + (i & 1) * 256;
            int e = 16384 + (i >> 1) * 4096 + swz32(c >> 2, c & 3);
            *(us8*)&mem[e] = pw[i];
        }
        __syncthreads();

        // prefetch next step's weight tile
        if (s < 7) {
            int sn = s + 1, kkn = (sn & 3) * 32;
            const unsigned short* ph = (sn >> 2) ? Wvhi : Wkhi;
            const unsigned short* po = (sn >> 2) ? Wvlo : Wklo;
#pragma unroll
            for (int i = 0; i < 4; i++) {
                const unsigned short* pl = (i >> 1) ? po : ph;
                int c = tid + (i & 1) * 256;
                pw[i] = *(const us8*)(pl + (size_t)(c >> 2) * 128 + (c & 3) * 8 + kkn);
            }
        }

        int kk = (s & 3) * 32;
        bf16x8 xh[2], xl[2];
#pragma unroll
        for (int mt = 0; mt < 2; mt++) {
            int row = R + mt * 16 + ln15;
            int ei = (row * 128 + kk + quad * 8) ^ xorx;
            xh[mt] = *(const bf16x8*)&mem[ei];
            xl[mt] = *(const bf16x8*)&mem[8192 + ei];
        }
#pragma unroll
        for (int nt = 0; nt < 4; nt++) {
            int eb = 16384 + swz32(Cb + nt * 16 + ln15, quad);
            bf16x8 wh = *(const bf16x8*)&mem[eb];
            bf16x8 wl = *(const bf16x8*)&mem[4096 + eb];
#pragma unroll
            for (int mt = 0; mt < 2; mt++) {
                acc[mt][nt] = __builtin_amdgcn_mfma_f32_16x16x32_bf16(xh[mt], wh, acc[mt][nt], 0, 0, 0);
                acc[mt][nt] = __builtin_amdgcn_mfma_f32_16x16x32_bf16(xh[mt], wl, acc[mt][nt], 0, 0, 0);
                acc[mt][nt] = __builtin_amdgcn_mfma_f32_16x16x32_bf16(xl[mt], wh, acc[mt][nt], 0, 0, 0);
            }
        }

        if (s == 3) { // k epilogue; reuse accumulators for v
#pragma unroll
            for (int mt = 0; mt < 2; mt++)
#pragma unroll
                for (int nt = 0; nt < 4; nt++)
#pragma unroll
                    for (int r = 0; r < 4; r++) {
                        size_t o = (size_t)(m0 + R + mt * 16 + quad * 4 + r) * 128
                                 + Cb + nt * 16 + ln15;
                        kout[o] = acc[mt][nt][r] + bbk[nt];
                        acc[mt][nt][r] = 0.f;
                    }
        }
        if (s < 7) __syncthreads();
    }

#pragma unroll
    for (int mt = 0; mt < 2; mt++)
#pragma unroll
        for (int nt = 0; nt < 4; nt++)
#pragma unroll
            for (int r = 0; r < 4; r++) {
                size_t o = (size_t)(m0 + R + mt * 16 + quad * 4 + r) * 128
                         + Cb + nt * 16 + ln15;
                vout[o] = acc[mt][nt][r] + bbv[nt];
            }
}

// =================== init slots + LN + q (one block per slot row) ============
__global__ __launch_bounds__(128) void init_lnq_kernel(
    const float* __restrict__ noise, const float* __restrict__ smu,
    const float* __restrict__ sls, const float* __restrict__ g_s,
    const float* __restrict__ b_s, const float4* __restrict__ WqT4,
    const float* __restrict__ bq, float* __restrict__ slots,
    float* __restrict__ q)
{
    __shared__ float s_l[128];
    __shared__ float red[4];
    const int row = blockIdx.x, tid = threadIdx.x;
    const int k = row % 3;
    float x = smu[k * 128 + tid] + expf(sls[k * 128 + tid]) * noise[row * 128 + tid];
    slots[row * 128 + tid] = x;

    float s = x, s2 = x * x;
#pragma unroll
    for (int off = 32; off >= 1; off >>= 1) {
        s += __shfl_down(s, off, 64); s2 += __shfl_down(s2, off, 64);
    }
    if ((tid & 63) == 0) { red[tid >> 6] = s; red[2 + (tid >> 6)] = s2; }
    __syncthreads();
    float S = red[0] + red[1], S2 = red[2] + red[3];
    float m = S * (1.f / 128.f);
    float r = rsqrtf(S2 * (1.f / 128.f) - m * m + EPS);
    s_l[tid] = (x - m) * r * g_s[tid] + b_s[tid];
    __syncthreads();

    float a = bq[tid];
#pragma unroll 8
    for (int kq = 0; kq < 32; kq++) {
        float4 w = WqT4[kq * 128 + tid];
        a += s_l[4 * kq] * w.x + s_l[4 * kq + 1] * w.y
           + s_l[4 * kq + 2] * w.z + s_l[4 * kq + 3] * w.w;
    }
    q[row * 128 + tid] = a;
}

// ============ fused attention: logits -> softmax(K=3) -> partial updates =====
// k in registers (coalesced, used 3x); v staged to LDS up-front (latency
// hidden under logits); q_l stored with +1-per-32 gap (bank-conflict-free).
__global__ __launch_bounds__(256) void attn_kernel(
    const float* __restrict__ q, const float* __restrict__ kbuf,
    const float* __restrict__ vbuf, float* __restrict__ upd_part,
    float* __restrict__ attn_out, int write_attn)
{
    __shared__ float q_l[3][132];
    __shared__ __align__(16) float kv[64][132];
    __shared__ float lg[3][64];
    __shared__ float w_l[3][64];
    const int b = blockIdx.y, chunk = blockIdx.x, n0 = chunk * 64, tid = threadIdx.x;

    for (int idx = tid; idx < 384; idx += 256) {
        int s = idx >> 7, c = idx & 127;
        q_l[s][c + (c >> 5)] = q[b * 384 + idx];
    }
    const float4* vg = (const float4*)(vbuf + ((size_t)b * 1024 + n0) * 128);
    for (int idx = tid; idx < 2048; idx += 256) {
        int n = idx >> 5, c = (idx & 31) * 4;
        *(float4*)&kv[n][c] = vg[idx];
    }
    const int n = tid >> 2, q4 = tid & 3;
    float4 kr[8];
    const float4* kg4 = (const float4*)(kbuf + ((size_t)b * 1024 + n0 + n) * 128 + q4 * 32);
#pragma unroll
    for (int i = 0; i < 8; i++) kr[i] = kg4[i];
    __syncthreads();

    { // logits: thread = (token n, quarter q4)
        const float* q0 = &q_l[0][q4 * 33];
        const float* q1 = &q_l[1][q4 * 33];
        const float* q2 = &q_l[2][q4 * 33];
        float p0 = 0.f, p1 = 0.f, p2 = 0.f;
#pragma unroll
        for (int i = 0; i < 8; i++) {
            float kx[4] = {kr[i].x, kr[i].y, kr[i].z, kr[i].w};
#pragma unroll
            for (int j = 0; j < 4; j++) {
                float vv = kx[j];
                p0 += q0[4 * i + j] * vv;
                p1 += q1[4 * i + j] * vv;
                p2 += q2[4 * i + j] * vv;
            }
        }
        p0 += __shfl_xor(p0, 1, 64); p0 += __shfl_xor(p0, 2, 64);
        p1 += __shfl_xor(p1, 1, 64); p1 += __shfl_xor(p1, 2, 64);
        p2 += __shfl_xor(p2, 1, 64); p2 += __shfl_xor(p2, 2, 64);
        if (q4 == 0) {
            lg[0][n] = p0 * SCALE; lg[1][n] = p1 * SCALE; lg[2][n] = p2 * SCALE;
        }
    }
    __syncthreads();

    if (tid < 64) { // softmax over the 3 slots for token n=tid
        float l0 = lg[0][tid], l1 = lg[1][tid], l2 = lg[2][tid];
        float m = fmaxf(l0, fmaxf(l1, l2));
        float e0 = expf(l0 - m), e1 = expf(l1 - m), e2 = expf(l2 - m);
        float inv = 1.f / (e0 + e1 + e2);
        w_l[0][tid] = e0 * inv; w_l[1][tid] = e1 * inv; w_l[2][tid] = e2 * inv;
        if (write_attn) {
            attn_out[b * 3072 + n0 + tid]        = e0 * inv;
            attn_out[b * 3072 + 1024 + n0 + tid] = e1 * inv;
            attn_out[b * 3072 + 2048 + n0 + tid] = e2 * inv;
        }
    }
    __syncthreads();

    if (tid < 128) {
        float p0 = 0.f, p1 = 0.f, p2 = 0.f;
#pragma unroll 8
        for (int nn = 0; nn < 64; nn++) {
            float vv = kv[nn][tid];
            p0 += w_l[0][nn] * vv; p1 += w_l[1][nn] * vv; p2 += w_l[2][nn] * vv;
        }
        size_t base = (((size_t)b * 16 + chunk) * 3) * 128 + tid;
        upd_part[base]       = p0;
        upd_part[base + 128] = p1;
        upd_part[base + 256] = p2;
    }
}

// ====== fused GRU cell + LN + MLP residual + (LN_s + q for next iter) ========
// 384 threads: one gate-output per thread (coalesced WT4 panels), K-split for
// W2/Wq. Per-dot accumulation order identical to the row-major version.
__global__ __launch_bounds__(384) void gru_mlp_kernel(
    const float* __restrict__ slots_in, const float* __restrict__ upd_part,
    const float4* __restrict__ WihT4, const float* __restrict__ bih,
    const float4* __restrict__ WhhT4, const float* __restrict__ bhh,
    const float* __restrict__ g_m, const float* __restrict__ b_m,
    const float4* __restrict__ W1T4, const float* __restrict__ b1,
    const float4* __restrict__ W2T4, const float* __restrict__ b2,
    const float* __restrict__ g_s, const float* __restrict__ b_s,
    const float4* __restrict__ WqT4, const float* __restrict__ bq,
    float* __restrict__ slots_out, float* __restrict__ q_out, int write_q)
{
    __shared__ float u2[2][128];
    __shared__ float u_l[128], h_l[128];
    __shared__ float r_l[128], z_l[128], in_l[128], hn_l[128];
    __shared__ float n_l[128], hid_l[256], w2p[256];
    __shared__ float red[4];
    const int row = blockIdx.x, tid = threadIdx.x;
    const int bb_ = row / 3, ss = row - bb_ * 3;

    if (tid < 256) {
        int col = tid & 127, half = tid >> 7;
        const float* up = upd_part + (((size_t)bb_ * 16 + half * 8) * 3 + ss) * 128 + col;
        float u = 0.f;
#pragma unroll
        for (int c = 0; c < 8; c++) u += up[(size_t)c * 384];
        u2[half][col] = u;
        if (half == 0) h_l[col] = slots_in[row * 128 + col];
    }
    __syncthreads();
    if (tid < 128) u_l[tid] = u2[0][tid] + u2[1][tid];
    __syncthreads();

    { // gates: thread t computes Wih-dot and Whh-dot for gate-output t
        float gi = bih[tid], gh = bhh[tid];
#pragma unroll 8
        for (int kq = 0; kq < 32; kq++) {
            float4 a = WihT4[kq * 384 + tid];
            float4 c = WhhT4[kq * 384 + tid];
            gi += u_l[4 * kq] * a.x + u_l[4 * kq + 1] * a.y
                + u_l[4 * kq + 2] * a.z + u_l[4 * kq + 3] * a.w;
            gh += h_l[4 * kq] * c.x + h_l[4 * kq + 1] * c.y
                + h_l[4 * kq + 2] * c.z + h_l[4 * kq + 3] * c.w;
        }
        if (tid < 128)      r_l[tid] = 1.f / (1.f + expf(-(gi + gh)));
        else if (tid < 256) z_l[tid - 128] = 1.f / (1.f + expf(-(gi + gh)));
        else { in_l[tid - 256] = gi; hn_l[tid - 256] = gh; }
    }
    __syncthreads();

    float hnew = 0.f;
    if (tid < 128) {
        float nn = tanhf(in_l[tid] + r_l[tid] * hn_l[tid]);
        hnew = (1.f - z_l[tid]) * nn + z_l[tid] * h_l[tid];
        float s = hnew, s2 = hnew * hnew;
#pragma unroll
        for (int off = 32; off >= 1; off >>= 1) {
            s += __shfl_down(s, off, 64); s2 += __shfl_down(s2, off, 64);
        }
        if ((tid & 63) == 0) { red[tid >> 6] = s; red[2 + (tid >> 6)] = s2; }
    }
    __syncthreads();
    if (tid < 128) {
        float S = red[0] + red[1], S2 = red[2] + red[3];
        float m1 = S * (1.f / 128.f);
        float r1 = rsqrtf(S2 * (1.f / 128.f) - m1 * m1 + EPS);
        n_l[tid] = (hnew - m1) * r1 * g_m[tid] + b_m[tid];
    }
    __syncthreads();

    if (tid < 256) { // W1 + gelu
        float a = b1[tid];
#pragma unroll 8
        for (int kq = 0; kq < 32; kq++) {
            float4 w = W1T4[kq * 256 + tid];
            a += n_l[4 * kq] * w.x + n_l[4 * kq + 1] * w.y
               + n_l[4 * kq + 2] * w.z + n_l[4 * kq + 3] * w.w;
        }
        a = 0.5f * a * (1.f + erff(a * 0.70710678118654752f));
        hid_l[tid] = a;
    }
    __syncthreads();

    if (tid < 256) { // W2, K=256 split in halves
        int out = tid & 127, half = tid >> 7;
        float p = 0.f;
#pragma unroll 8
        for (int kq = half * 32; kq < half * 32 + 32; kq++) {
            float4 w = W2T4[kq * 128 + out];
            p += hid_l[4 * kq] * w.x + hid_l[4 * kq + 1] * w.y
               + hid_l[4 * kq + 2] * w.z + hid_l[4 * kq + 3] * w.w;
        }
        w2p[tid] = p;
    }
    __syncthreads();

    float snew = 0.f;
    if (tid < 128) {
        snew = hnew + b2[tid] + (w2p[tid] + w2p[128 + tid]);
        slots_out[row * 128 + tid] = snew;
    }

    if (write_q) {
        if (tid < 128) {
            float t1 = snew, t2 = snew * snew;
#pragma unroll
            for (int off = 32; off >= 1; off >>= 1) {
                t1 += __shfl_down(t1, off, 64); t2 += __shfl_down(t2, off, 64);
            }
            if ((tid & 63) == 0) { red[tid >> 6] = t1; red[2 + (tid >> 6)] = t2; }
        }
        __syncthreads();
        if (tid < 128) {
            float T = red[0] + red[1], T2 = red[2] + red[3];
            float m2 = T * (1.f / 128.f);
            float r2 = rsqrtf(T2 * (1.f / 128.f) - m2 * m2 + EPS);
            n_l[tid] = (snew - m2) * r2 * g_s[tid] + b_s[tid];
        }
        __syncthreads();
        if (tid < 256) { // Wq, K=128 split in halves
            int out = tid & 127, half = tid >> 7;
            float p = (half == 0) ? bq[out] : 0.f;
#pragma unroll 8
            for (int kq = half * 16; kq < half * 16 + 16; kq++) {
                float4 w = WqT4[kq * 128 + out];
                p += n_l[4 * kq] * w.x + n_l[4 * kq + 1] * w.y
                   + n_l[4 * kq + 2] * w.z + n_l[4 * kq + 3] * w.w;
            }
            w2p[tid] = p;
        }
        __syncthreads();
        if (tid < 128) q_out[row * 128 + tid] = w2p[tid] + w2p[128 + tid];
    }
}

// ============================================================================
extern "C" void kernel_launch(void* const* d_in, const int* in_sizes, int n_in,
                              void* d_out, int out_size, void* d_ws, size_t ws_size,
                              hipStream_t stream)
{
    const float* patch   = (const float*)d_in[0];
    const float* noise   = (const float*)d_in[1];
    const float* slot_mu = (const float*)d_in[2];
    const float* slot_ls = (const float*)d_in[3];
    const float* Wp = (const float*)d_in[4];  const float* bp = (const float*)d_in[5];
    const float* g_in = (const float*)d_in[6]; const float* b_in = (const float*)d_in[7];
    const float* Wq = (const float*)d_in[8];  const float* bq = (const float*)d_in[9];
    const float* Wk = (const float*)d_in[10]; const float* bk = (const float*)d_in[11];
    const float* Wv = (const float*)d_in[12]; const float* bv = (const float*)d_in[13];
    const float* Wih = (const float*)d_in[14]; const float* bih = (const float*)d_in[15];
    const float* Whh = (const float*)d_in[16]; const float* bhh = (const float*)d_in[17];
    const float* g_s = (const float*)d_in[18]; const float* b_s = (const float*)d_in[19];
    const float* W1 = (const float*)d_in[20]; const float* b1 = (const float*)d_in[21];
    const float* W2 = (const float*)d_in[22]; const float* b2 = (const float*)d_in[23];
    const float* g_m = (const float*)d_in[24]; const float* b_m = (const float*)d_in[25];

    // ---- workspace layout ----
    float* kbuf = (float*)d_ws;                                   // 16777216 f32
    float* vbuf = kbuf + 16777216;                                // 16777216 f32
    unsigned short* w_hi = (unsigned short*)(vbuf + 16777216);    // 57344
    unsigned short* w_lo = w_hi + 57344;                          // 57344
    unsigned short* wp_hi = w_hi,        * wp_lo = w_lo;
    unsigned short* wk_hi = w_hi + 24576,* wk_lo = w_lo + 24576;
    unsigned short* wv_hi = w_hi + 40960,* wv_lo = w_lo + 40960;
    float4* wt4 = (float4*)(w_lo + 57344);                        // 45056 float4
    float4* wihT4 = wt4;
    float4* whhT4 = wt4 + 12288;
    float4* w1T4  = wt4 + 24576;
    float4* w2T4  = wt4 + 32768;
    float4* wqT4  = wt4 + 40960;
    float* slots = (float*)(wt4 + 45056);                         // 49152 f32
    float* qbuf  = slots + 49152;                                 // 49152 f32
    float* part  = qbuf + 49152;                                  // 786432 f32

    float* out_slots = (float*)d_out;                             // (B,K,H)
    float* out_attn  = (float*)d_out + 49152;                     // (B,K,N)

    split_weights_kernel<<<224, 256, 0, stream>>>(Wp, Wk, Wv, w_hi, w_lo);
    pack_weights_kernel<<<176, 256, 0, stream>>>(Wih, Whh, W1, W2, Wq, wt4);

    // X = LN(patch @ Wp^T + bp) kept in LDS; k,v written directly.
    fused_proj_kv_kernel<<<2048, 256, 0, stream>>>(
        patch, wp_hi, wp_lo, wk_hi, wk_lo, wv_hi, wv_lo,
        bp, g_in, b_in, bk, bv, kbuf, vbuf);

    // slots init + LN + q0
    init_lnq_kernel<<<384, 128, 0, stream>>>(noise, slot_mu, slot_ls,
                                             g_s, b_s, wqT4, bq, slots, qbuf);

    for (int it = 0; it < 3; it++) {
        attn_kernel<<<dim3(16, 128), 256, 0, stream>>>(
            qbuf, kbuf, vbuf, part, out_attn, it == 2 ? 1 : 0);
        gru_mlp_kernel<<<384, 384, 0, stream>>>(
            slots, part, wihT4, bih, whhT4, bhh, g_m, b_m, w1T4, b1, w2T4, b2,
            g_s, b_s, wqT4, bq,
            (it == 2) ? out_slots : slots, qbuf, it == 2 ? 0 : 1);
    }
}